// Round 24
// baseline (238.301 us; speedup 1.0000x reference)
//
#include <hip/hip_runtime.h>
#include <math.h>

#define NTOK   262144
#define DIM    64
#define NCODE  1024
#define LOSSOFF (NTOK*DIM)          // 16777216
#define IDXOFF  (NTOK*DIM + 1)

// Margin covers: ref's fp32 quantization reorder (2*ulp(D~64..128) ~ 3.05e-5
// worst tail) + MFMA-split dd error (<= ~3e-7). 4e-5 holds with headroom.
#define MARGIN 4e-5f
#define RCAP   65536

// ws float-offsets
#define OFF_BC     0               // 1024 f
#define OFF_CBHI   1024            // ushort[65536] = 32768 f (plain rows)
#define OFF_CBMID  33792           // 32768 f (plain rows)
#define OFF_RCNT   66560           // 1 int
#define OFF_CORR   66561           // 1 float
#define OFF_RLIST  66562           // 65536 int
#define OFF_BLK    132098          // 2048 f
#define WS_FLOATS  134146

typedef __attribute__((ext_vector_type(8))) short short8;
typedef __attribute__((ext_vector_type(4))) float f32x4;

__device__ __forceinline__ ushort bf16rn(float f) {
    unsigned u = __float_as_uint(f);
    return (ushort)((u + 0x7fffu + ((u >> 16) & 1u)) >> 16);
}
__device__ __forceinline__ float bf16tof(ushort h) {
    return __uint_as_float(((unsigned)h) << 16);
}

// prep: split codebook into bf16 hi/mid planes (plain row-major; codes are
// gathered straight into registers now, no LDS staging of the codebook).
__global__ __launch_bounds__(256) void vq_prep_cb(const float* __restrict__ cb,
                                                  float* __restrict__ ws) {
    int c = blockIdx.x * 256 + threadIdx.x;
    if (c == 0) { ((int*)ws)[OFF_RCNT] = 0; ws[OFF_CORR] = 0.f; }
    if (c >= NCODE) return;
    ushort* cbh = (ushort*)(ws + OFF_CBHI);
    ushort* cbm = (ushort*)(ws + OFF_CBMID);
    const float4* p = (const float4*)(cb + (size_t)c * DIM);
    float a0 = 0.f, a1 = 0.f, a2 = 0.f, a3 = 0.f;
#pragma unroll
    for (int i = 0; i < 16; i++) {
        float4 v = p[i];
        a0 = fmaf(v.x, v.x, a0); a1 = fmaf(v.y, v.y, a1);
        a2 = fmaf(v.z, v.z, a2); a3 = fmaf(v.w, v.w, a3);
        ushort4 h, m;
        h.x = bf16rn(v.x); m.x = bf16rn(v.x - bf16tof(h.x));
        h.y = bf16rn(v.y); m.y = bf16rn(v.y - bf16tof(h.y));
        h.z = bf16rn(v.z); m.z = bf16rn(v.z - bf16tof(h.z));
        h.w = bf16rn(v.w); m.w = bf16rn(v.w - bf16tof(h.w));
        ((ushort4*)(cbh + (size_t)c * 64))[i] = h;
        ((ushort4*)(cbm + (size_t)c * 64))[i] = m;
    }
    ws[OFF_BC + c] = (a0 + a1) + (a2 + a3);   // exact R2 prep chain
}

// Code-resident scan: 8 waves/block; wave w holds codes [w*128,w*128+128) as
// MFMA A-fragments IN REGISTERS (loaded once) + their Bc. Tokens stream
// through LDS (32/round, pre-split bf16 hi/mid, conversion once per block).
// Per 16-token tile a wave does 48 MFMAs per 4 ds_read_b128 (4x less LDS
// than R18). Cross-wave merge in LDS: ascending wave = ascending code range
// -> exact first-min; partition-correct second-best. Distance values
// bit-identical to R18 (same 6-MFMA chain, same operands).
__global__ __launch_bounds__(512)
__attribute__((amdgpu_waves_per_eu(2, 2)))
void vq_scan(const float* __restrict__ x,
             const float* __restrict__ cbf,
             float* __restrict__ out,
             float* __restrict__ ws) {
    __shared__ uint4 xls[2][256];     // 8KB: [tile][token*16 + plane*8 + slot]
    __shared__ float mb[8][32], ms2[8][32];
    __shared__ int   mi[8][32];
    __shared__ int   idxs[128];
    __shared__ float red[8];

    const float* Bc = ws + OFF_BC;
    const ushort* cbh = (const ushort*)(ws + OFF_CBHI);
    const ushort* cbm = (const ushort*)(ws + OFF_CBMID);

    int tid = threadIdx.x, lane = tid & 63, wv = tid >> 6;
    int col = lane & 15, q = lane >> 4, q4 = q * 4;
    int wbase = wv * 128;

    // ---- load this wave's 128 codes as A-fragments (once per block) ----
    short8 Ah0[8], Ah1[8], Am0[8], Am1[8];
    float4 bq4[8];
    {
        const ushort* ch = cbh + (size_t)(wbase + col) * 64 + q * 8;
        const ushort* cm = cbm + (size_t)(wbase + col) * 64 + q * 8;
#pragma unroll
        for (int s = 0; s < 8; ++s) {
            Ah0[s] = __builtin_bit_cast(short8, *(const uint4*)(ch + s * 1024));
            Ah1[s] = __builtin_bit_cast(short8, *(const uint4*)(ch + s * 1024 + 32));
            Am0[s] = __builtin_bit_cast(short8, *(const uint4*)(cm + s * 1024));
            Am1[s] = __builtin_bit_cast(short8, *(const uint4*)(cm + s * 1024 + 32));
            bq4[s] = *(const float4*)(Bc + wbase + s * 16 + q4);
        }
    }

    // staging task decomposition (one 16B granule per thread per round)
    int st_tile = tid >> 8, srem = tid & 255;
    int st_tok = srem >> 4, st_pl = (srem >> 3) & 1, st_oct = srem & 7;
    int st_dst = st_tok * 16 + st_pl * 8 + (st_oct ^ (st_tok & 7));
    // X-fragment ds_read offsets (token row = col; zero-conflict pattern)
    int rx_h0 = col * 16 + (q ^ (col & 7));
    int rx_h1 = col * 16 + ((4 + q) ^ (col & 7));
    int rx_m0 = col * 16 + 8 + (q ^ (col & 7));
    int rx_m1 = col * 16 + 8 + ((4 + q) ^ (col & 7));

    for (int r = 0; r < 4; ++r) {
        int tb0 = blockIdx.x * 128 + r * 32;
        // ---- stage 32 tokens: load f32, split hi/mid, swizzled ds_write ----
        {
            const float* xr = x + (size_t)(tb0 + st_tile * 16 + st_tok) * 64 + st_oct * 8;
            float4 v0 = *(const float4*)(xr);
            float4 v1 = *(const float4*)(xr + 4);
            float vv[8] = {v0.x, v0.y, v0.z, v0.w, v1.x, v1.y, v1.z, v1.w};
            short8 g;
#pragma unroll
            for (int j = 0; j < 8; ++j) {
                ushort h = bf16rn(vv[j]);
                g[j] = st_pl ? (short)bf16rn(vv[j] - bf16tof(h))   // mid (exact residual)
                             : (short)h;                           // hi
            }
            xls[st_tile][st_dst] = __builtin_bit_cast(uint4, g);
        }
        __syncthreads();   // B1: stage visible

        // ---- compute: 2 tiles x 8 sub-tiles x 6 MFMA ----
#pragma unroll
        for (int tile = 0; tile < 2; ++tile) {
            short8 Xh0 = __builtin_bit_cast(short8, xls[tile][rx_h0]);
            short8 Xh1 = __builtin_bit_cast(short8, xls[tile][rx_h1]);
            short8 Xm0 = __builtin_bit_cast(short8, xls[tile][rx_m0]);
            short8 Xm1 = __builtin_bit_cast(short8, xls[tile][rx_m1]);
            float best[4] = {3.4e38f, 3.4e38f, 3.4e38f, 3.4e38f};
            float sec[4]  = {3.4e38f, 3.4e38f, 3.4e38f, 3.4e38f};
            int bbase[4] = {0, 0, 0, 0};
#pragma unroll
            for (int s = 0; s < 8; ++s) {
                f32x4 acc = {0.f, 0.f, 0.f, 0.f};
                acc = __builtin_amdgcn_mfma_f32_16x16x32_bf16(Ah0[s], Xh0, acc, 0, 0, 0);
                acc = __builtin_amdgcn_mfma_f32_16x16x32_bf16(Ah1[s], Xh1, acc, 0, 0, 0);
                acc = __builtin_amdgcn_mfma_f32_16x16x32_bf16(Ah0[s], Xm0, acc, 0, 0, 0);
                acc = __builtin_amdgcn_mfma_f32_16x16x32_bf16(Ah1[s], Xm1, acc, 0, 0, 0);
                acc = __builtin_amdgcn_mfma_f32_16x16x32_bf16(Am0[s], Xh0, acc, 0, 0, 0);
                acc = __builtin_amdgcn_mfma_f32_16x16x32_bf16(Am1[s], Xh1, acc, 0, 0, 0);
                int bv = wbase + s * 16 + q4;
                float bqv[4] = {bq4[s].x, bq4[s].y, bq4[s].z, bq4[s].w};
#pragma unroll
                for (int rr = 0; rr < 4; ++rr) {
                    float d = fmaf(-2.f, acc[rr], bqv[rr]);
                    bool lt = d < best[rr];
                    sec[rr] = __builtin_amdgcn_fmed3f(d, best[rr], sec[rr]);
                    best[rr] = fminf(best[rr], d);
                    bbase[rr] = lt ? bv : bbase[rr];
                }
            }
            // finalize this wave's 128-code partial for its 16 tokens
            float b = best[0], s2 = sec[0];
            int bi = bbase[0];
#pragma unroll
            for (int rr = 1; rr < 4; ++rr) {
                float ob = best[rr];
                int oi = bbase[rr] + rr;
                s2 = fminf(fminf(s2, sec[rr]), fmaxf(b, ob));
                bool lt = (ob < b) || (ob == b && oi < bi);
                b = lt ? ob : b; bi = lt ? oi : bi;
            }
#pragma unroll
            for (int off = 16; off <= 32; off <<= 1) {
                float ob = __shfl_xor(b, off, 64);
                float os = __shfl_xor(s2, off, 64);
                int   oi = __shfl_xor(bi, off, 64);
                s2 = fminf(fminf(s2, os), fmaxf(b, ob));
                bool lt = (ob < b) || (ob == b && oi < bi);
                b = lt ? ob : b; bi = lt ? oi : bi;
            }
            if (lane < 16) {
                mb[wv][tile * 16 + lane] = b;
                ms2[wv][tile * 16 + lane] = s2;
                mi[wv][tile * 16 + lane] = bi;
            }
        }
        __syncthreads();   // B2: partials visible

        // ---- cross-wave merge (32 tokens, exact first-min, partition sec) ----
        if (tid < 32) {
            float b = 3.4e38f, s2 = 3.4e38f;
            int bi = 0;
#pragma unroll
            for (int w = 0; w < 8; ++w) {    // ascending w = ascending codes
                float ob = mb[w][tid], os = ms2[w][tid];
                int oi = mi[w][tid];
                s2 = fminf(fminf(s2, os), fmaxf(b, ob));
                bool lt = (ob < b) || (ob == b && oi < bi);
                b = lt ? ob : b; bi = lt ? oi : bi;
            }
            int token = tb0 + tid;
            out[IDXOFF + token] = (float)bi;
            idxs[r * 32 + tid] = bi;
            if (s2 - b < MARGIN) {
                int pos = atomicAdd((int*)ws + OFF_RCNT, 1);
                if (pos < RCAP) ((int*)ws)[OFF_RLIST + pos] = token;
            }
        }
        __syncthreads();   // B3: merge done; xls/mb reusable
    }

    // ---- fused quantized + loss epilogue (refine corrects flagged rows) ----
    float se = 0.f;
    int tokb0 = blockIdx.x * 128;
#pragma unroll
    for (int i = 0; i < 4; ++i) {
        int gi = i * 512 + tid;
        int tok = gi >> 4, qd = gi & 15;
        int ci = idxs[tok];
        float4 xvv = *(const float4*)(x + (size_t)(tokb0 + tok) * 64 + qd * 4);
        float4 qv = *(const float4*)(cbf + (size_t)ci * 64 + qd * 4);
        float d0 = qv.x - xvv.x, d1 = qv.y - xvv.y;
        float d2 = qv.z - xvv.z, d3 = qv.w - xvv.w;
        float4 o;
        o.x = xvv.x + d0; o.y = xvv.y + d1; o.z = xvv.z + d2; o.w = xvv.w + d3;
        *(float4*)(out + (size_t)(tokb0 + tok) * 64 + qd * 4) = o;
        se += d0 * d0 + d1 * d1 + d2 * d2 + d3 * d3;
    }
    for (int off = 32; off; off >>= 1) se += __shfl_down(se, off, 64);
    if (lane == 0) red[wv] = se;
    __syncthreads();
    if (tid == 0) {
        float s = 0.f;
#pragma unroll
        for (int i = 0; i < 8; ++i) s += red[i];
        ws[OFF_BLK + blockIdx.x] = s;
    }
}

// exact fp32 re-scan for flagged tokens; fixes quantized rows + loss delta.
__global__ __launch_bounds__(256) void vq_refine(const float* __restrict__ x,
                                                 const float* __restrict__ cb,
                                                 float* __restrict__ out,
                                                 float* __restrict__ ws) {
    __shared__ float ctile[128][64];               // 32KB
    __shared__ float xs[8][64];
    __shared__ float As[8];
    __shared__ int   tokid[8], oidx[8], nidx[8];
    __shared__ unsigned long long rkeys[8][128];   // 8KB
    __shared__ float dred[4];

    int cnt = min(((int*)ws)[OFF_RCNT], RCAP);
    if (cnt <= 0) return;
    int ngroups = (cnt + 7) >> 3;
    int tid = threadIdx.x;
    int code = tid & 127, th = tid >> 7;

    for (int grp = blockIdx.x; grp < ngroups; grp += gridDim.x) {
        if (tid < 8) {
            int i = grp * 8 + tid;
            int t = ((int*)ws)[OFF_RLIST + min(i, cnt - 1)];
            tokid[tid] = t;
            oidx[tid] = (int)out[IDXOFF + t];
        }
        __syncthreads();
#pragma unroll
        for (int it = 0; it < 2; ++it) {
            int idx = it * 256 + tid;
            xs[idx >> 6][idx & 63] = x[(size_t)tokid[idx >> 6] * 64 + (idx & 63)];
        }
        __syncthreads();
        if (tid < 8) {   // exact R2 A-chain
            float a0 = 0.f, a1 = 0.f, a2 = 0.f, a3 = 0.f;
#pragma unroll
            for (int kc = 0; kc < 16; ++kc) {
                float4 xk = *(const float4*)(xs[tid] + kc * 4);
                a0 = fmaf(xk.x, xk.x, a0); a1 = fmaf(xk.y, xk.y, a1);
                a2 = fmaf(xk.z, xk.z, a2); a3 = fmaf(xk.w, xk.w, a3);
            }
            As[tid] = (a0 + a1) + (a2 + a3);
        }

        unsigned long long bk[4] = {~0ull, ~0ull, ~0ull, ~0ull};
        int tb = th * 4;

        for (int pass = 0; pass < 8; ++pass) {
            int cbase = pass * 128;
            __syncthreads();
#pragma unroll
            for (int it = 0; it < 8; ++it) {
                int gi = it * 256 + tid;
                int cc = gi >> 4, qq = gi & 15;
                float4 v = *(const float4*)(cb + (size_t)(cbase + cc) * 64 + qq * 4);
                *(float4*)&ctile[cc][(qq ^ (cc & 15)) * 4] = v;
            }
            __syncthreads();

            float p0 = 0.f, p1 = 0.f, p2 = 0.f, p3 = 0.f;
#pragma unroll
            for (int qq = 0; qq < 16; ++qq) {
                float4 cv = *(const float4*)&ctile[code][(qq ^ (code & 15)) * 4];
                float4 x0 = *(const float4*)(xs[tb + 0] + qq * 4);
                float4 x1 = *(const float4*)(xs[tb + 1] + qq * 4);
                float4 x2 = *(const float4*)(xs[tb + 2] + qq * 4);
                float4 x3 = *(const float4*)(xs[tb + 3] + qq * 4);
                p0 = fmaf(x0.x, cv.x, p0); p0 = fmaf(x0.y, cv.y, p0);
                p0 = fmaf(x0.z, cv.z, p0); p0 = fmaf(x0.w, cv.w, p0);
                p1 = fmaf(x1.x, cv.x, p1); p1 = fmaf(x1.y, cv.y, p1);
                p1 = fmaf(x1.z, cv.z, p1); p1 = fmaf(x1.w, cv.w, p1);
                p2 = fmaf(x2.x, cv.x, p2); p2 = fmaf(x2.y, cv.y, p2);
                p2 = fmaf(x2.z, cv.z, p2); p2 = fmaf(x2.w, cv.w, p2);
                p3 = fmaf(x3.x, cv.x, p3); p3 = fmaf(x3.y, cv.y, p3);
                p3 = fmaf(x3.z, cv.z, p3); p3 = fmaf(x3.w, cv.w, p3);
            }
            float bn = ws[OFF_BC + cbase + code];
            int gcode = cbase + code;
            float pv[4] = {p0, p1, p2, p3};
#pragma unroll
            for (int j = 0; j < 4; ++j) {
                float s = As[tb + j] + bn;
                float d = fmaf(-2.0f, pv[j], s);   // == fl(s - 2p)
                unsigned long long key =
                    (((unsigned long long)__float_as_uint(d)) << 32) | (unsigned)gcode;
                bk[j] = min(bk[j], key);
            }
        }
        __syncthreads();
#pragma unroll
        for (int j = 0; j < 4; ++j) rkeys[tb + j][code] = bk[j];
        __syncthreads();

        int wv2 = tid >> 6, lane = tid & 63;
#pragma unroll
        for (int u = 0; u < 2; ++u) {
            int tt = wv2 * 2 + u;
            unsigned long long k = min(rkeys[tt][lane], rkeys[tt][lane + 64]);
#pragma unroll
            for (int off = 32; off; off >>= 1)
                k = min(k, (unsigned long long)__shfl_xor((long long)k, off, 64));
            if (lane == 0) {
                int ni = (int)(unsigned)(k & 0xffffffffull);
                nidx[tt] = ni;
                if (grp * 8 + tt < cnt) out[IDXOFF + tokid[tt]] = (float)ni;
            }
        }
        __syncthreads();

        float delta = 0.f;
        {
            int tok = tid >> 5, e2 = (tid & 31) * 2;
            if (grp * 8 + tok < cnt) {
                int nw = nidx[tok], od = oidx[tok];
                if (nw != od) {
                    float x0 = xs[tok][e2], x1 = xs[tok][e2 + 1];
                    float qn0 = cb[(size_t)nw * 64 + e2], qn1 = cb[(size_t)nw * 64 + e2 + 1];
                    float qo0 = cb[(size_t)od * 64 + e2], qo1 = cb[(size_t)od * 64 + e2 + 1];
                    float dn0 = qn0 - x0, dn1 = qn1 - x1;
                    float do0 = qo0 - x0, do1 = qo1 - x1;
                    out[(size_t)tokid[tok] * 64 + e2]     = x0 + dn0;
                    out[(size_t)tokid[tok] * 64 + e2 + 1] = x1 + dn1;
                    delta = (dn0 * dn0 + dn1 * dn1) - (do0 * do0 + do1 * do1);
                }
            }
        }
        for (int off = 32; off; off >>= 1) delta += __shfl_down(delta, off, 64);
        if ((tid & 63) == 0) dred[tid >> 6] = delta;
        __syncthreads();
        if (tid == 0) {
            float dsum = (dred[0] + dred[1]) + (dred[2] + dred[3]);
            if (dsum != 0.f) atomicAdd(ws + OFF_CORR, dsum);
        }
        __syncthreads();
    }
}

__global__ __launch_bounds__(256) void vq_loss2(float* __restrict__ out,
                                                const float* __restrict__ ws) {
    const float* blk = ws + OFF_BLK;
    __shared__ double sd[256];
    double s = 0.0;
    for (int i = threadIdx.x; i < 2048; i += 256) s += (double)blk[i];
    sd[threadIdx.x] = s;
    __syncthreads();
    for (int off = 128; off; off >>= 1) {
        if (threadIdx.x < off) sd[threadIdx.x] += sd[threadIdx.x + off];
        __syncthreads();
    }
    if (threadIdx.x == 0) {
        double tot = sd[0] + (double)ws[OFF_CORR];
        out[LOSSOFF] = (float)(1.25 * tot / ((double)NTOK * (double)DIM));
    }
}

extern "C" void kernel_launch(void* const* d_in, const int* in_sizes, int n_in,
                              void* d_out, int out_size, void* d_ws, size_t ws_size,
                              hipStream_t stream) {
    (void)in_sizes; (void)n_in; (void)out_size; (void)ws_size;
    const float* x = (const float*)d_in[0];
    const float* cb = (const float*)d_in[1];
    float* out = (float*)d_out;
    float* ws = (float*)d_ws;

    hipLaunchKernelGGL(vq_prep_cb, dim3(4), dim3(256), 0, stream, cb, ws);
    hipLaunchKernelGGL(vq_scan, dim3(2048), dim3(512), 0, stream, x, cb, out, ws);
    hipLaunchKernelGGL(vq_refine, dim3(1024), dim3(256), 0, stream, x, cb, out, ws);
    hipLaunchKernelGGL(vq_loss2, dim3(1), dim3(256), 0, stream, out, ws);
}